// Round 7
// baseline (191.735 us; speedup 1.0000x reference)
//
#include <hip/hip_runtime.h>
#include <math.h>

#define BT    34   // sequence length
#define TPR   9    // threads per row; thread j owns tokens {j, j+9, j+18, j+27}
#define RPB   28   // rows per block (28*9 = 252 active threads of 256)
#define BLOCK 256
// grid = ceil(32768/28) = 1171 <= 5 blocks/CU * 256 CU -> fully resident, no tail

typedef float v2f __attribute__((ext_vector_type(2)));
typedef float v4f __attribute__((ext_vector_type(4)));
typedef _Float16 half2_t __attribute__((ext_vector_type(2)));

// log2(e)/sqrt(3): folds the 1/sqrt(hd) scale AND the exp->exp2 conversion into q.
#define QSCALE 0.83294037332470f

#if __has_builtin(__builtin_amdgcn_exp2f)
#define EXP2(x) __builtin_amdgcn_exp2f(x)
#else
#define EXP2(x) exp2f(x)
#endif

__device__ __forceinline__ void ln6(const float* x, const float* g, const float* b, float* o) {
  float mu = (x[0]+x[1]+x[2]+x[3]+x[4]+x[5]) * (1.0f/6.0f);
  float v = 0.f;
  #pragma unroll
  for (int c = 0; c < 6; ++c) { float d = x[c]-mu; v += d*d; }
  float inv = rsqrtf(v * (1.0f/6.0f) + 1e-5f);
  #pragma unroll
  for (int c = 0; c < 6; ++c) o[c] = (x[c]-mu)*inv*g[c] + b[c];
}

// LDS union: kv view (row*17+slot)*12 floats = 28*17*12*4 = 22848 B
//            logits view (row*34+t)*7 u32 (fp16 pairs) = 28*34*7*4 = 26656 B
__global__ __launch_bounds__(BLOCK, 5)
void addtrans_kernel(const int* __restrict__ idx,
                     const float* __restrict__ tok_emb,
                     const float* __restrict__ pos_params,
                     const float* __restrict__ z10_enc,
                     const float* __restrict__ special_enc,
                     const float* __restrict__ wq,
                     const float* __restrict__ wk,
                     const float* __restrict__ wv,
                     const float* __restrict__ wo,
                     const float* __restrict__ ln1_g, const float* __restrict__ ln1_b,
                     const float* __restrict__ ln2_g, const float* __restrict__ ln2_b,
                     const float* __restrict__ lnf_g, const float* __restrict__ lnf_b,
                     const float* __restrict__ ffn_w1, const float* __restrict__ ffn_b1,
                     const float* __restrict__ ffn_w2, const float* __restrict__ ffn_b2,
                     const float* __restrict__ head_w,
                     float* __restrict__ out, int B)
{
  __shared__ __align__(16) unsigned s_u32[RPB*BT*7];
  __shared__ float s_te[42];
  __shared__ float s_pos[BT*3];
  __shared__ float s_wq[18], s_wk[18], s_wv[18], s_wo[36], s_hw[18];
  __shared__ float s_g1[6], s_b1[6], s_g2[6], s_b2[6], s_gf[6], s_bf[6];
  __shared__ float s_w1[12], s_w2[12], s_fb1[2], s_fb2[6];

  float* s_kvf = (float*)s_u32;
  const int tid = threadIdx.x;

  // ---- stage params / build pos table ----
  if (tid < 42) s_te[tid] = tok_emb[tid];
  if (tid < 18) { s_wq[tid]=wq[tid]; s_wk[tid]=wk[tid]; s_wv[tid]=wv[tid]; s_hw[tid]=head_w[tid]; }
  if (tid < 36) s_wo[tid] = wo[tid];
  if (tid < 12) { s_w1[tid]=ffn_w1[tid]; s_w2[tid]=ffn_w2[tid]; }
  if (tid < 6)  { s_g1[tid]=ln1_g[tid]; s_b1[tid]=ln1_b[tid];
                  s_g2[tid]=ln2_g[tid]; s_b2[tid]=ln2_b[tid];
                  s_gf[tid]=lnf_g[tid]; s_bf[tid]=lnf_b[tid];
                  s_fb2[tid]=ffn_b2[tid]; }
  if (tid < 2)  s_fb1[tid] = ffn_b1[tid];
  if (tid < BT) {
    int p = tid, f;
    if (p < 10) f = p;
    else if (p == 10) f = 11;
    else if (p < 21) f = p - 11;
    else if (p == 21) f = 12;
    else if (p < 33) { int z = p - 22; f = (z < 10) ? z : 10; }
    else f = 13;
    float e0, e1, e2;
    if (f < 10) {
      float amp = pos_params[0], ph = pos_params[1], sl = pos_params[2], of = pos_params[3];
      float ang = 0.62831853071795864769f * (float)f + ph;  // 2*pi*f/10 + phase
      e0 = amp * cosf(ang); e1 = amp * sinf(ang); e2 = sl * (float)f + of;
    } else if (f == 10) { e0 = z10_enc[0]; e1 = z10_enc[1]; e2 = z10_enc[2]; }
    else { int u = f - 11; e0 = special_enc[u*3]; e1 = special_enc[u*3+1]; e2 = special_enc[u*3+2]; }
    s_pos[tid*3+0] = e0; s_pos[tid*3+1] = e1; s_pos[tid*3+2] = e2;
  }
  __syncthreads();

  const int row = tid / TPR;           // 0..28 (28 => lanes 252..255 inactive)
  const int j   = tid - row * TPR;     // 0..8
  const int b0  = blockIdx.x * RPB;
  const int b   = b0 + row;
  int nrows = B - b0; if (nrows > RPB) nrows = RPB; if (nrows < 0) nrows = 0;
  const bool active = (row < RPB) && (b < B);
  const bool has3 = (j < 7);           // token j+27 exists only for j<7

  int tok[4];
  tok[0] = j; tok[1] = j + 9; tok[2] = j + 18; tok[3] = has3 ? (j + 27) : 33;

  v2f qp[4][3];
  int vid[4];

  // helper lambdas
  auto make_h = [&](int v, int t, float* h) {
    float x6[6];
    x6[0] = s_te[v*3+0]; x6[1] = s_te[v*3+1]; x6[2] = s_te[v*3+2];
    x6[3] = s_pos[t*3+0]; x6[4] = s_pos[t*3+1]; x6[5] = s_pos[t*3+2];
    ln6(x6, s_g1, s_b1, h);
  };
  auto publish_kv = [&](const float* h, int slot) {
    float k6[6], v6[6];
    #pragma unroll
    for (int c = 0; c < 6; ++c) {
      k6[c] = h[3]*s_wk[c] + h[4]*s_wk[6+c] + h[5]*s_wk[12+c];
      v6[c] = h[0]*s_wv[c] + h[1]*s_wv[6+c] + h[2]*s_wv[12+c];
    }
    v4f* kvp = (v4f*)&s_kvf[(row*17 + slot)*12];
    kvp[0] = (v4f){k6[0], k6[3], k6[1], k6[4]};
    kvp[1] = (v4f){k6[2], k6[5], v6[0], v6[3]};
    kvp[2] = (v4f){v6[1], v6[4], v6[2], v6[5]};
  };

  // ---- embed + ln1 + q for 4 tokens; publish pass-1 kv (keys 0..16) ----
  if (active) {
    const int base = b * BT;
    #pragma unroll
    for (int s = 0; s < 4; ++s) vid[s] = idx[base + tok[s]];
    #pragma unroll
    for (int s = 0; s < 4; ++s) {
      float h[6];
      make_h(vid[s], tok[s], h);
      float q6[6];
      #pragma unroll
      for (int c = 0; c < 6; ++c)
        q6[c] = h[3]*s_wq[c] + h[4]*s_wq[6+c] + h[5]*s_wq[12+c];
      qp[s][0] = (v2f){q6[0]*QSCALE, q6[3]*QSCALE};
      qp[s][1] = (v2f){q6[1]*QSCALE, q6[4]*QSCALE};
      qp[s][2] = (v2f){q6[2]*QSCALE, q6[5]*QSCALE};
      if (s == 0) publish_kv(h, j);                 // keys 0..8
      if (s == 1 && j <= 7) publish_kv(h, j + 9);   // keys 9..16
    }
  }
  __syncthreads();

  // ---- attention: pass 1 (keys 0..16) ----
  v2f l[4]; v2f o[4][3];
  #pragma unroll
  for (int s = 0; s < 4; ++s) {
    l[s] = (v2f){0.f,0.f};
    o[s][0] = (v2f){0.f,0.f}; o[s][1] = (v2f){0.f,0.f}; o[s][2] = (v2f){0.f,0.f};
  }
  const v4f* kvb = (const v4f*)&s_kvf[row * (17*12)];

#define LOADKV(kk) \
    v4f A = kvb[(kk)*3+0], Bv = kvb[(kk)*3+1], C = kvb[(kk)*3+2]; \
    v2f kA = (v2f){A.x, A.y}, kB = (v2f){A.z, A.w}, kC = (v2f){Bv.x, Bv.y}; \
    v2f vA = (v2f){Bv.z, Bv.w}, vB = (v2f){C.x, C.y}, vC = (v2f){C.z, C.w};
#define QSTEP(s, PRED) do { \
    v2f sc = qp[s][0]*kA + qp[s][1]*kB + qp[s][2]*kC; \
    v2f p = (v2f){EXP2(sc.x), EXP2(sc.y)}; \
    if (!(PRED)) p = (v2f){0.f,0.f}; \
    l[s] += p; o[s][0] += p*vA; o[s][1] += p*vB; o[s][2] += p*vC; \
  } while(0)

  if (active) {
    #pragma unroll 3
    for (int k = 0; k < 9; ++k) {        // q0 masked; q1,q2,q3 unmasked
      LOADKV(k);
      QSTEP(0, k <= j); QSTEP(1, true); QSTEP(2, true); QSTEP(3, true);
    }
    #pragma unroll 4
    for (int k = 9; k < 17; ++k) {       // q1 masked; q2,q3 unmasked
      LOADKV(k);
      QSTEP(1, k <= j+9); QSTEP(2, true); QSTEP(3, true);
    }
  }
  __syncthreads();                       // pass-1 reads complete

  // ---- republish kv for keys 17..33 into slots 0..16 ----
  if (active) {
    float h[6];
    make_h(vid[2], tok[2], h);           // t2 = j+18 -> slot j+1
    publish_kv(h, j + 1);
    if (j <= 6) {                        // t3 = j+27 -> slot j+10
      make_h(vid[3], tok[3], h);
      publish_kv(h, j + 10);
    }
    if (j == 8) {                        // t1 = 17 -> slot 0
      make_h(vid[1], 17, h);
      publish_kv(h, 0);
    }
  }
  __syncthreads();                       // pass-2 kv ready

  // ---- attention: pass 2 (keys 17..33, slot k = key-17) ----
  if (active) {
    {                                    // k=0 (key 17): q1 only for j==8
      LOADKV(0);
      QSTEP(1, j >= 8); QSTEP(2, true); QSTEP(3, true);
    }
    #pragma unroll 3
    for (int k = 1; k < 10; ++k) {       // q2 masked; q3 unmasked
      LOADKV(k);
      QSTEP(2, k <= j+1); QSTEP(3, true);
    }
    #pragma unroll 4
    for (int k = 10; k < 17; ++k) {      // q3 masked
      LOADKV(k);
      QSTEP(3, k <= j+10);
    }
  }
  __syncthreads();                       // pass-2 reads done; buffer free for logits

  // ---- epilogue per token: o/l, wo, residual, ln2, FFN(gelu), lnf, head -> fp16 LDS ----
  if (active) {
    #pragma unroll
    for (int s = 0; s < 4; ++s) {
      if (s == 3 && !has3) continue;
      const int t = tok[s];
      const float ia = __builtin_amdgcn_rcpf(l[s].x);
      const float ib = __builtin_amdgcn_rcpf(l[s].y);
      float a6[6] = { o[s][0].x*ia, o[s][1].x*ia, o[s][2].x*ia,
                      o[s][0].y*ib, o[s][1].y*ib, o[s][2].y*ib };
      float xrv[6] = { s_te[vid[s]*3+0], s_te[vid[s]*3+1], s_te[vid[s]*3+2],
                       s_pos[t*3+0],     s_pos[t*3+1],     s_pos[t*3+2] };
      float xn[6];
      #pragma unroll
      for (int c = 0; c < 6; ++c) {
        xn[c] = xrv[c]
              + a6[0]*s_wo[c]    + a6[1]*s_wo[6+c]  + a6[2]*s_wo[12+c]
              + a6[3]*s_wo[18+c] + a6[4]*s_wo[24+c] + a6[5]*s_wo[30+c];
      }
      float h2v[6];
      ln6(xn, s_g2, s_b2, h2v);
      float a0 = s_fb1[0], a1 = s_fb1[1];
      #pragma unroll
      for (int d = 0; d < 6; ++d) { a0 += h2v[d]*s_w1[d*2]; a1 += h2v[d]*s_w1[d*2+1]; }
      const float g0 = 0.5f*a0*(1.0f + erff(a0*0.70710678118654752440f));
      const float g1 = 0.5f*a1*(1.0f + erff(a1*0.70710678118654752440f));
      #pragma unroll
      for (int c = 0; c < 6; ++c) xn[c] += g0*s_w2[c] + g1*s_w2[6+c] + s_fb2[c];
      float xf[6];
      ln6(xn, s_gf, s_bf, xf);
      float y0 = 0.f, y1 = 0.f, y2 = 0.f;
      #pragma unroll
      for (int c = 0; c < 6; ++c) {
        y0 += xf[c]*s_hw[c*3+0]; y1 += xf[c]*s_hw[c*3+1]; y2 += xf[c]*s_hw[c*3+2];
      }
      unsigned* lp = &s_u32[(row*BT + t)*7];
      #pragma unroll
      for (int u = 0; u < 7; ++u) {
        const int c0 = 2*u, c1 = 2*u+1;
        float f0 = y0*s_te[c0*3+0] + y1*s_te[c0*3+1] + y2*s_te[c0*3+2];
        float f1 = y0*s_te[c1*3+0] + y1*s_te[c1*3+1] + y2*s_te[c1*3+2];
        lp[u] = __builtin_bit_cast(unsigned, __builtin_amdgcn_cvt_pkrtz(f0, f1));
      }
    }
  }
  __syncthreads();

  // ---- coalesced store: 2 fp16-pairs -> 4 floats -> one 16B nontemporal store ----
  if (nrows > 0) {
    const int n4 = nrows * (BT*14/4);    // 119 v4f per row
    float* dst = out + (size_t)b0 * (BT*14);
    for (int i = tid; i < n4; i += BLOCK) {
      half2_t ha = __builtin_bit_cast(half2_t, s_u32[2*i]);
      half2_t hb = __builtin_bit_cast(half2_t, s_u32[2*i+1]);
      v4f f = (v4f){(float)ha.x, (float)ha.y, (float)hb.x, (float)hb.y};
      __builtin_nontemporal_store(f, (v4f*)(dst + 4*i));
    }
  }
}

extern "C" void kernel_launch(void* const* d_in, const int* in_sizes, int n_in,
                              void* d_out, int out_size, void* d_ws, size_t ws_size,
                              hipStream_t stream) {
  const int B = in_sizes[0] / BT;                 // 32768
  const int grid = (B + RPB - 1) / RPB;           // 1171 -> fully resident at 5 blocks/CU
  addtrans_kernel<<<grid, BLOCK, 0, stream>>>(
      (const int*)d_in[0],   (const float*)d_in[1], (const float*)d_in[2],
      (const float*)d_in[3], (const float*)d_in[4], (const float*)d_in[5],
      (const float*)d_in[6], (const float*)d_in[7], (const float*)d_in[8],
      (const float*)d_in[9], (const float*)d_in[10], (const float*)d_in[11],
      (const float*)d_in[12], (const float*)d_in[13], (const float*)d_in[14],
      (const float*)d_in[15], (const float*)d_in[16], (const float*)d_in[17],
      (const float*)d_in[18], (const float*)d_in[19],
      (float*)d_out, B);
}